// Round 11
// baseline (299.019 us; speedup 1.0000x reference)
//
#include <hip/hip_runtime.h>
#include <math.h>
#include <stdint.h>

typedef __bf16 bf16;
typedef bf16  bf16x8 __attribute__((ext_vector_type(8)));
typedef float f32x4  __attribute__((ext_vector_type(4)));

// Problem constants
constexpr int Bb  = 2;
constexpr int Ss  = 2048;
constexpr int Dd  = 1024;
constexpr int Hh  = 16;
constexpr int DHh = 64;
constexpr int MLPd = 4096;
constexpr int ROWS = Bb * Ss;        // 4096
constexpr int NC  = Ss / 64;         // 32 chunks of 64
constexpr int BH  = Bb * Hh;         // 32
constexpr float EPS_LN = 1e-6f;
constexpr float KEPS   = 1e-3f;

// ---------------------------------------------------------------------------
// async global->LDS copy, 16B per lane (global_load_lds_dwordx4)
// ---------------------------------------------------------------------------
__device__ __forceinline__ void async_copy16(const bf16* g, bf16* l) {
    __builtin_amdgcn_global_load_lds(
        (__attribute__((address_space(1))) void*)g,
        (__attribute__((address_space(3))) void*)l,
        16, 0, 0);
}

// 64-wide swizzled LDS tile index (conflict-free fragment pattern)
__device__ __forceinline__ int swz64(int row, int col) {
    return row * 64 + (((col >> 3) ^ row) & 7) * 8 + (col & 7);
}

// ---------------------------------------------------------------------------
// Fused preprocessing: one dispatch, 16384 blocks x 256 threads.
//   sector 0: LN1 row + bf16 copy of inputs row
//   sector 1: 4x 1024x1024 weight convert+transpose
//   sector 2: w1 convert; sector 3: w2 convert
// ---------------------------------------------------------------------------
__global__ __launch_bounds__(256) void preproc_kernel(
    const float* __restrict__ inputs,
    const float* __restrict__ ln1_scale, const float* __restrict__ ln1_bias,
    bf16* __restrict__ xln, bf16* __restrict__ inp_bf,
    const float* __restrict__ wq, const float* __restrict__ wk,
    const float* __restrict__ wv, const float* __restrict__ wo,
    bf16* __restrict__ wqT, bf16* __restrict__ wkT,
    bf16* __restrict__ wvT, bf16* __restrict__ woT,
    const float* __restrict__ w1, bf16* __restrict__ w1T,
    const float* __restrict__ w2, bf16* __restrict__ w2T)
{
    __shared__ float tile[32][33];
    __shared__ float ssum[4], ssq[4];
    const int blk = blockIdx.x;
    const int sector = blk >> 12;

    if (sector == 0) {
        const int row = blk;
        const float* xr = inputs + (size_t)row * Dd;
        const int c0 = threadIdx.x * 4;
        float vals[4];
        float sum = 0.f, sumsq = 0.f;
#pragma unroll
        for (int i = 0; i < 4; i++) {
            float v = xr[c0 + i];
            vals[i] = v;
            sum += v;
            sumsq += v * v;
        }
#pragma unroll
        for (int off = 32; off > 0; off >>= 1) {
            sum   += __shfl_down(sum, off);
            sumsq += __shfl_down(sumsq, off);
        }
        const int wave = threadIdx.x >> 6;
        if ((threadIdx.x & 63) == 0) { ssum[wave] = sum; ssq[wave] = sumsq; }
        __syncthreads();
        const float tot   = ssum[0] + ssum[1] + ssum[2] + ssum[3];
        const float totsq = ssq[0] + ssq[1] + ssq[2] + ssq[3];
        const float mean = tot * (1.f / Dd);
        const float var  = totsq * (1.f / Dd) - mean * mean;
        const float r = rsqrtf(var + EPS_LN);
        bf16* orow = xln + (size_t)row * Dd;
        bf16* irow = inp_bf + (size_t)row * Dd;
#pragma unroll
        for (int i = 0; i < 4; i++) {
            irow[c0 + i] = (bf16)vals[i];
            orow[c0 + i] = (bf16)((vals[i] - mean) * r * ln1_scale[c0 + i] + ln1_bias[c0 + i]);
        }
    } else {
        const float* in; bf16* out; int K, N, bx, by;
        if (sector == 1) {
            const int local = blk - 4096;
            const int z = local >> 10;
            in  = (z == 0) ? wq : (z == 1) ? wk : (z == 2) ? wv : wo;
            out = (z == 0) ? wqT : (z == 1) ? wkT : (z == 2) ? wvT : woT;
            K = 1024; N = 1024;
            bx = local & 31; by = (local >> 5) & 31;
        } else if (sector == 2) {
            const int local = blk - 8192;
            in = w1; out = w1T; K = 1024; N = 4096;
            bx = local & 127; by = local >> 7;
        } else {
            const int local = blk - 12288;
            in = w2; out = w2T; K = 4096; N = 1024;
            bx = local & 31; by = local >> 5;
        }
        const int k0 = by * 32, n0 = bx * 32;
        const int tx = threadIdx.x & 31, ty = threadIdx.x >> 5;
#pragma unroll
        for (int i = 0; i < 32; i += 8)
            tile[ty + i][tx] = in[(size_t)(k0 + ty + i) * N + n0 + tx];
        __syncthreads();
#pragma unroll
        for (int i = 0; i < 32; i += 8)
            out[(size_t)(n0 + ty + i) * K + k0 + tx] = (bf16)tile[tx][ty + i];
    }
}

// ---------------------------------------------------------------------------
// Wo split-K reduce + residual + LN2, one block per row:
//   x2 = bf16(psA + psB + inp_bf);  yln = LN(x2)
// ---------------------------------------------------------------------------
__global__ __launch_bounds__(256) void wo_reduce_ln(
    const float* __restrict__ psA, const float* __restrict__ psB,
    const bf16* __restrict__ inp,
    const float* __restrict__ scale, const float* __restrict__ bias,
    bf16* __restrict__ x2, bf16* __restrict__ yln)
{
    const int row = blockIdx.x;
    const int c0 = threadIdx.x * 4;
    const size_t base = (size_t)row * Dd + c0;
    float vals[4];
    float sum = 0.f, sumsq = 0.f;
#pragma unroll
    for (int i = 0; i < 4; i++) {
        float v = psA[base + i] + psB[base + i] + (float)inp[base + i];
        v = (float)(bf16)v;      // x2 is stored bf16; LN stats on rounded value
        vals[i] = v;
        sum += v;
        sumsq += v * v;
    }
#pragma unroll
    for (int off = 32; off > 0; off >>= 1) {
        sum   += __shfl_down(sum, off);
        sumsq += __shfl_down(sumsq, off);
    }
    __shared__ float ssum[4], ssq[4];
    const int wave = threadIdx.x >> 6;
    if ((threadIdx.x & 63) == 0) { ssum[wave] = sum; ssq[wave] = sumsq; }
    __syncthreads();
    const float tot   = ssum[0] + ssum[1] + ssum[2] + ssum[3];
    const float totsq = ssq[0] + ssq[1] + ssq[2] + ssq[3];
    const float mean = tot * (1.f / Dd);
    const float var  = totsq * (1.f / Dd) - mean * mean;
    const float r = rsqrtf(var + EPS_LN);
#pragma unroll
    for (int i = 0; i < 4; i++) {
        x2[base + i]  = (bf16)vals[i];
        yln[base + i] = (bf16)((vals[i] - mean) * r * scale[c0 + i] + bias[c0 + i]);
    }
}

// ---------------------------------------------------------------------------
// MLP2 split-K reduce: out = psA(out) + psB + bias + x2.  grid 4096 x 256.
// ---------------------------------------------------------------------------
__global__ __launch_bounds__(256) void mlp2_reduce(
    float* __restrict__ outp, const float* __restrict__ psB,
    const float* __restrict__ b2, const bf16* __restrict__ x2)
{
    const size_t i4 = ((size_t)blockIdx.x * 256 + threadIdx.x) * 4;
    const int col = (int)(i4 & 1023);
    f32x4 a = *(const f32x4*)&outp[i4];
    f32x4 b = *(const f32x4*)&psB[i4];
    f32x4 o;
#pragma unroll
    for (int j = 0; j < 4; j++)
        o[j] = a[j] + b[j] + b2[col + j] + (float)x2[i4 + j];
    *(f32x4*)&outp[i4] = o;
}

// ---------------------------------------------------------------------------
// bf16 MFMA GEMM: C[4096, NDIM] = A @ B, BT[N][K], compile-time dims.
// 128 x TN tile, BK=128; optional KSPLIT; 1-D grid, XCD-aware swizzle.
// Measured law: staging volume M*N*K*2*(1/128+1/TN) drains at ~14 TB/s with
// BK=128 @ 2 blocks/CU (R6/R7), but only ~8.5 TB/s with BK=64 (R10) — the
// deeper K-tile keeps 2x loads in flight per barrier drain. BK=128's ~6e6
// bank conflicts are priced into the 14 TB/s.
// ---------------------------------------------------------------------------
enum { EP_QKV = 0, EP_NONE = 1, EP_RES = 2, EP_GELU = 3, EP_BIAS_RES = 4, EP_PARTIAL = 5 };

template <int TN, int BK, int NDIM, int KDIM, int MODE, int KSPLIT>
__global__ __launch_bounds__(256, 2) void mfma_gemm(const bf16* __restrict__ A,
                                                    const bf16* __restrict__ BT,
                                                    void* __restrict__ Cout,
                                                    const float* __restrict__ bias,
                                                    const void* __restrict__ res,
                                                    bf16* __restrict__ out2,
                                                    bf16* __restrict__ out3)
{
    constexpr int WCT = TN / 2;      // wave col tile
    constexpr int NJ  = TN / 32;     // col fragments per wave
    constexpr int NS  = BK / 32;     // MFMA k-steps per tile
    constexpr int CPR = BK / 8;      // 16B chunks per row
    constexpr int RPI = 2048 / BK;   // rows staged per issue
    constexpr int GRIDY = 32;        // M/128
    constexpr int RPX = GRIDY / 8;   // row-blocks per XCD band (4)
    constexpr int TILES = GRIDY * (NDIM / TN);
    constexpr int KLEN  = KDIM / KSPLIT;
    __shared__ bf16 As[128 * BK];
    __shared__ bf16 Bs[TN * BK];
    const int t = threadIdx.x;
    const int wave = t >> 6, lane = t & 63;

    // K-split + XCD-aware block swizzle
    const int bid0 = blockIdx.x;
    const int ks  = (KSPLIT > 1) ? (bid0 / TILES) : 0;
    const int bid = (KSPLIT > 1) ? (bid0 % TILES) : bid0;
    const int xcd = bid & 7, idx = bid >> 3;
    const int row0 = (xcd * RPX + (idx & (RPX - 1))) * 128;
    const int col0 = (idx / RPX) * TN;

    const int wr = wave >> 1, wc = wave & 1;

    // staging indices
    const int srow = t / CPR;
    const int gch  = (t % CPR) ^ (srow & 7);
    const int sdst = t * 8;

    // hoisted global pointers (advance by BK per K-iter)
    const bf16* gA = A  + (size_t)(row0 + srow) * KDIM + ks * KLEN + gch * 8;
    const bf16* gB = BT + (size_t)(col0 + srow) * KDIM + ks * KLEN + gch * 8;

    // fragment indices
    const int m = lane & 15, quad = lane >> 4;
    const int mx7 = m & 7;

    f32x4 acc[4][NJ] = {};

    for (int k0 = 0; k0 < KLEN; k0 += BK) {
        __syncthreads();
#pragma unroll
        for (int i = 0; i < 128 / RPI; i++)
            async_copy16(gA + (size_t)i * RPI * KDIM, &As[i * 2048 + sdst]);
#pragma unroll
        for (int i = 0; i < TN / RPI; i++)
            async_copy16(gB + (size_t)i * RPI * KDIM, &Bs[i * 2048 + sdst]);
        __syncthreads();

#pragma unroll
        for (int s = 0; s < NS; s++) {
            const int pco = ((s * 4 + quad) ^ mx7) * 8;
            bf16x8 aF[4], bF[NJ];
#pragma unroll
            for (int i = 0; i < 4; i++)
                aF[i] = *(const bf16x8*)&As[(wr * 64 + i * 16 + m) * BK + pco];
#pragma unroll
            for (int j = 0; j < NJ; j++)
                bF[j] = *(const bf16x8*)&Bs[(wc * WCT + j * 16 + m) * BK + pco];
#pragma unroll
            for (int i = 0; i < 4; i++)
#pragma unroll
                for (int j = 0; j < NJ; j++)
                    acc[i][j] = __builtin_amdgcn_mfma_f32_16x16x32_bf16(
                        aF[i], bF[j], acc[i][j], 0, 0, 0);
        }
        gA += BK;
        gB += BK;
    }

    // epilogue: C/D layout col=lane&15, row=quad*4+reg (HW-verified)
#pragma unroll
    for (int i = 0; i < 4; i++) {
#pragma unroll
        for (int j = 0; j < NJ; j++) {
#pragma unroll
            for (int r = 0; r < 4; r++) {
                const int row = row0 + wr * 64 + i * 16 + quad * 4 + r;
                const int col = col0 + wc * WCT + j * 16 + m;
                float val = acc[i][j][r];
                if constexpr (MODE == EP_QKV) {
                    // per-element third routing
                    const int third = col >> 10;
                    bf16* dst = (third == 0) ? (bf16*)Cout : (third == 1) ? out2 : out3;
                    if (third < 2) val = fmaxf(val, 0.f) + KEPS;
                    dst[(size_t)row * 1024 + (col & 1023)] = (bf16)val;
                } else if constexpr (MODE == EP_NONE) {
                    ((bf16*)Cout)[(size_t)row * NDIM + col] = (bf16)val;
                } else if constexpr (MODE == EP_RES) {
                    val += (float)((const bf16*)res)[(size_t)row * NDIM + col];
                    ((bf16*)Cout)[(size_t)row * NDIM + col] = (bf16)val;
                } else if constexpr (MODE == EP_GELU) {
                    val += bias[col];
                    const float u = 0.7978845608028654f * (val + 0.044715f * val * val * val);
                    const float e = __expf(2.f * u);
                    val = val * (1.f - 1.f / (e + 1.f));
                    ((bf16*)Cout)[(size_t)row * NDIM + col] = (bf16)val;
                } else if constexpr (MODE == EP_BIAS_RES) {
                    val += bias[col] + (float)((const bf16*)res)[(size_t)row * NDIM + col];
                    ((float*)Cout)[(size_t)row * NDIM + col] = val;
                } else {
                    // EP_PARTIAL: raw fp32 partial; ks selects the buffer
                    float* dst = (ks == 0) ? (float*)Cout : (float*)out2;
                    dst[(size_t)row * NDIM + col] = val;
                }
            }
        }
    }
}

// ---------------------------------------------------------------------------
// Phase A (MFMA): KV[m][d], ksum[m]. kvs bf16. grid=(NC,BH)
// ---------------------------------------------------------------------------
__global__ __launch_bounds__(256) void chunk_kv_kernel(const bf16* __restrict__ phik,
                                                       const bf16* __restrict__ v,
                                                       bf16* __restrict__ kvs,
                                                       float* __restrict__ ksums)
{
    const int c = blockIdx.x, bh = blockIdx.y;
    const int b = bh >> 4, h = bh & 15;
    __shared__ bf16 Kt[64 * 64];   // [m][s]
    __shared__ bf16 Vt[64 * 64];   // [d][s]
    const int t = threadIdx.x;
    const int wave = t >> 6, lane = t & 63;
    const int m16 = lane & 15, quad = lane >> 4;
    const int wr = wave >> 1, wc = wave & 1;
    const int f = t & 63, s4 = t >> 6;

#pragma unroll
    for (int i = 0; i < 16; i++) {
        const int s = s4 + 4 * i;
        const size_t g = ((size_t)((b * Ss + c * 64 + s) * Hh + h)) * DHh + f;
        Kt[swz64(f, s)] = phik[g];
        Vt[swz64(f, s)] = v[g];
    }
    __syncthreads();

    f32x4 acc[2][2] = {};
#pragma unroll
    for (int ks = 0; ks < 2; ks++) {
        bf16x8 aF[2], bF[2];
#pragma unroll
        for (int i = 0; i < 2; i++)
            aF[i] = *(const bf16x8*)&Kt[swz64(wr * 32 + i * 16 + m16, ks * 32 + quad * 8)];
#pragma unroll
        for (int j = 0; j < 2; j++)
            bF[j] = *(const bf16x8*)&Vt[swz64(wc * 32 + j * 16 + m16, ks * 32 + quad * 8)];
#pragma unroll
        for (int i = 0; i < 2; i++)
#pragma unroll
            for (int j = 0; j < 2; j++)
                acc[i][j] = __builtin_amdgcn_mfma_f32_16x16x32_bf16(
                    aF[i], bF[j], acc[i][j], 0, 0, 0);
    }

    const size_t base = ((size_t)bh * NC + c) * 4096;
#pragma unroll
    for (int i = 0; i < 2; i++)
#pragma unroll
        for (int j = 0; j < 2; j++)
#pragma unroll
            for (int r = 0; r < 4; r++) {
                const int mrow = wr * 32 + i * 16 + quad * 4 + r;
                const int dcol = wc * 32 + j * 16 + m16;
                kvs[base + mrow * 64 + dcol] = (bf16)acc[i][j][r];
            }

    if (t < 64) {
        float s_ = 0.f;
#pragma unroll
        for (int p = 0; p < 8; p++) {
            bf16x8 k8 = *(const bf16x8*)&Kt[t * 64 + p * 8];
#pragma unroll
            for (int e = 0; e < 8; e++) s_ += (float)k8[e];
        }
        ksums[((size_t)bh * NC + c) * 64 + t] = s_;
    }
}

// ---------------------------------------------------------------------------
// Phase B: exclusive prefix scan over chunks, element-parallel. kvs bf16.
// ---------------------------------------------------------------------------
__global__ __launch_bounds__(256) void scan_kernel(bf16* __restrict__ kvs,
                                                   float* __restrict__ ksums)
{
    const int e  = blockIdx.x * 256 + threadIdx.x;
    const int bh = blockIdx.y;
    float run = 0.f;
#pragma unroll 4
    for (int c = 0; c < NC; c++) {
        const size_t idx = ((size_t)bh * NC + c) * 4096 + e;
        const float val = (float)kvs[idx];
        kvs[idx] = (bf16)run;
        run += val;
    }
    if (blockIdx.x == 0 && threadIdx.x < 64) {
        float r = 0.f;
        for (int c = 0; c < NC; c++) {
            const size_t idx = ((size_t)bh * NC + c) * 64 + threadIdx.x;
            const float val = ksums[idx];
            ksums[idx] = r;
            r += val;
        }
    }
}

// ---------------------------------------------------------------------------
// Phase C (MFMA): per-chunk output. grid = (NC, BH)
// ---------------------------------------------------------------------------
__global__ __launch_bounds__(256) void attn_out_kernel(const bf16* __restrict__ phiq,
                                                       const bf16* __restrict__ phik,
                                                       const bf16* __restrict__ v,
                                                       const bf16* __restrict__ kvs,
                                                       const float* __restrict__ ksums,
                                                       bf16* __restrict__ attn)
{
    const int c = blockIdx.x, bh = blockIdx.y;
    const int b = bh >> 4, h = bh & 15;
    __shared__ bf16 Qs [64 * 64];
    __shared__ bf16 KVb[64 * 64];
    __shared__ bf16 Sm [64 * 64];
    __shared__ bf16 KVt[64 * 64];
    __shared__ float ksm[64], den[64];
    const int t = threadIdx.x;
    const int wave = t >> 6, lane = t & 63;
    const int m16 = lane & 15, quad = lane >> 4;
    const int wr = wave >> 1, wc = wave & 1;
    const int f = t & 63, s4 = t >> 6;

#pragma unroll
    for (int i = 0; i < 16; i++) {
        const int s = s4 + 4 * i;
        const size_t g = ((size_t)((b * Ss + c * 64 + s) * Hh + h)) * DHh + f;
        Qs [swz64(s, f)] = phiq[g];
        KVb[swz64(s, f)] = phik[g];
    }
    if (t < 64) ksm[t] = ksums[((size_t)bh * NC + c) * 64 + t];
    __syncthreads();

    // S = phiq @ phik^T
    f32x4 sacc[2][2] = {};
#pragma unroll
    for (int ks = 0; ks < 2; ks++) {
        bf16x8 aF[2], bF[2];
#pragma unroll
        for (int i = 0; i < 2; i++)
            aF[i] = *(const bf16x8*)&Qs [swz64(wr * 32 + i * 16 + m16, ks * 32 + quad * 8)];
#pragma unroll
        for (int j = 0; j < 2; j++)
            bF[j] = *(const bf16x8*)&KVb[swz64(wc * 32 + j * 16 + m16, ks * 32 + quad * 8)];
#pragma unroll
        for (int i = 0; i < 2; i++)
#pragma unroll
            for (int j = 0; j < 2; j++)
                sacc[i][j] = __builtin_amdgcn_mfma_f32_16x16x32_bf16(
                    aF[i], bF[j], sacc[i][j], 0, 0, 0);
    }
#pragma unroll
    for (int i = 0; i < 2; i++)
#pragma unroll
        for (int j = 0; j < 2; j++)
#pragma unroll
            for (int r = 0; r < 4; r++) {
                const int row = wr * 32 + i * 16 + quad * 4 + r;
                const int col = wc * 32 + j * 16 + m16;
                Sm[swz64(row, col)] = (bf16)((col <= row) ? sacc[i][j][r] : 0.f);
            }
    __syncthreads();

    // stage Vt[d][s'] and KVt[d][m]
#pragma unroll
    for (int i = 0; i < 16; i++) {
        const int s = s4 + 4 * i;
        const size_t g = ((size_t)((b * Ss + c * 64 + s) * Hh + h)) * DHh + f;
        KVb[swz64(f, s)] = v[g];
    }
    {
        const size_t base = ((size_t)bh * NC + c) * 4096;
#pragma unroll
        for (int i = 0; i < 16; i++) {
            const int e = t + 256 * i;
            KVt[swz64(e & 63, e >> 6)] = kvs[base + e];
        }
    }
    __syncthreads();

    // den
    if (t < 64) {
        float d_ = 0.f;
#pragma unroll
        for (int p = 0; p < 8; p++) {
            const int gc = (p ^ (t & 7)) * 8;
            bf16x8 q8 = *(const bf16x8*)&Qs[t * 64 + p * 8];
            bf16x8 s8 = *(const bf16x8*)&Sm[t * 64 + p * 8];
#pragma unroll
            for (int e = 0; e < 8; e++)
                d_ += (float)q8[e] * ksm[gc + e] + (float)s8[e];
        }
        den[t] = d_;
    }

    // O = S @ v + phiq @ KV_excl
    f32x4 oacc[2][2] = {};
#pragma unroll
    for (int ks = 0; ks < 2; ks++) {
        bf16x8 aF[2], bF[2];
#pragma unroll
        for (int i = 0; i < 2; i++)
            aF[i] = *(const bf16x8*)&Sm [swz64(wr * 32 + i * 16 + m16, ks * 32 + quad * 8)];
#pragma unroll
        for (int j = 0; j < 2; j++)
            bF[j] = *(const bf16x8*)&KVb[swz64(wc * 32 + j * 16 + m16, ks * 32 + quad * 8)];
#pragma unroll
        for (int i = 0; i < 2; i++)
#pragma unroll
            for (int j = 0; j < 2; j++)
                oacc[i][j] = __builtin_amdgcn_mfma_f32_16x16x32_bf16(
                    aF[i], bF[j], oacc[i][j], 0, 0, 0);
    }
#pragma unroll
    for (int ks = 0; ks < 2; ks++) {
        bf16x8 aF[2], bF[2];
#pragma unroll
        for (int i = 0; i < 2; i++)
            aF[i] = *(const bf16x8*)&Qs [swz64(wr * 32 + i * 16 + m16, ks * 32 + quad * 8)];
#pragma unroll
        for (int j = 0; j < 2; j++)
            bF[j] = *(const bf16x8*)&KVt[swz64(wc * 32 + j * 16 + m16, ks * 32 + quad * 8)];
#pragma unroll
        for (int i = 0; i < 2; i++)
#pragma unroll
            for (int j = 0; j < 2; j++)
                oacc[i][j] = __builtin_amdgcn_mfma_f32_16x16x32_bf16(
                    aF[i], bF[j], oacc[i][j], 0, 0, 0);
    }
    __syncthreads();

#pragma unroll
    for (int i = 0; i < 2; i++) {
#pragma unroll
        for (int r = 0; r < 4; r++) {
            const int row = wr * 32 + i * 16 + quad * 4 + r;
            const float dinv = 1.f / den[row];
#pragma unroll
            for (int j = 0; j < 2; j++) {
                const int col = wc * 32 + j * 16 + m16;
                attn[((size_t)((b * Ss + c * 64 + row) * Hh + h)) * DHh + col] =
                    (bf16)(oacc[i][j][r] * dinv);
            }
        }
    }
}

// ---------------------------------------------------------------------------
// Host launch
// ---------------------------------------------------------------------------
extern "C" void kernel_launch(void* const* d_in, const int* in_sizes, int n_in,
                              void* d_out, int out_size, void* d_ws, size_t ws_size,
                              hipStream_t stream)
{
    const float* inputs    = (const float*)d_in[0];
    const float* ln1_scale = (const float*)d_in[1];
    const float* ln1_bias  = (const float*)d_in[2];
    const float* wq        = (const float*)d_in[3];
    const float* wk        = (const float*)d_in[4];
    const float* wv        = (const float*)d_in[5];
    const float* wo        = (const float*)d_in[6];
    const float* ln2_scale = (const float*)d_in[7];
    const float* ln2_bias  = (const float*)d_in[8];
    const float* w1        = (const float*)d_in[9];
    const float* b1        = (const float*)d_in[10];
    const float* w2        = (const float*)d_in[11];
    const float* b2        = (const float*)d_in[12];
    float* out = (float*)d_out;

    // Workspace layout (byte offsets), with lifetime reuse:
    //  0  MB: xln bf16 -> attn bf16 -> MLP2 partial1 (fp32, 0-16MB)
    //  8  MB: q bf16 -> yln bf16
    //  16 MB: k,v (16-32) -> Wo partial0 fp32 (16-32) -> hbuf (16-48)
    //  32 MB: kvs bf16 (32-40) + gap -> Wo partial1 fp32 (32-48)
    //  48 MB: x2 bf16; 56 MB: inp_bf bf16
    //  64 MB: ksums; 64.25 MB: bf16 weights (24MB)
    char* ws = (char*)d_ws;
    bf16*  xln    = (bf16*)ws;
    bf16*  q      = (bf16*)(ws + (8ull  << 20));
    bf16*  k      = (bf16*)(ws + (16ull << 20));
    bf16*  v      = (bf16*)(ws + (24ull << 20));
    bf16*  kvs    = (bf16*)(ws + (32ull << 20));
    bf16*  x2     = (bf16*)(ws + (48ull << 20));
    bf16*  inp_bf = (bf16*)(ws + (56ull << 20));
    float* ksums  = (float*)(ws + (64ull << 20));
    bf16*  wqT    = (bf16*)(ws + (64ull << 20) + (1ull << 18));
    bf16*  wkT    = wqT + 1024 * 1024;
    bf16*  wvT    = wkT + 1024 * 1024;
    bf16*  woT    = wvT + 1024 * 1024;
    bf16*  w1T    = woT + 1024 * 1024;         // [4096][1024]
    bf16*  w2T    = w1T + 4096 * 1024;         // [1024][4096]
    bf16*  attn   = xln;
    bf16*  yln    = q;
    bf16*  hbuf   = k;                         // 32MB spanning 16-48MB
    float* psWo0  = (float*)(ws + (16ull << 20));   // 16MB
    float* psWo1  = (float*)(ws + (32ull << 20));   // 16MB
    float* psM2   = (float*)ws;                     // 16MB (xln/attn dead)

    // 0. Fused preprocessing
    preproc_kernel<<<16384, 256, 0, stream>>>(
        inputs, ln1_scale, ln1_bias, xln, inp_bf,
        wq, wk, wv, wo, wqT, wkT, wvT, woT, w1, w1T, w2, w2T);

    // 1. Fused QKV: 128x128 tile, BK=128, grid 768
    mfma_gemm<128, 128, 3072, 1024, EP_QKV, 1><<<dim3(24 * 32), 256, 0, stream>>>(
        xln, wqT, q, nullptr, nullptr, k, v);

    // 2-4. Chunked causal linear attention
    {
        dim3 gridA(NC, BH);
        chunk_kv_kernel<<<gridA, 256, 0, stream>>>(k, v, kvs, ksums);
        scan_kernel<<<dim3(4096 / 256, BH), 256, 0, stream>>>(kvs, ksums);
        attn_out_kernel<<<gridA, 256, 0, stream>>>(q, k, v, kvs, ksums, attn);
    }

    // 5. Wo: 128x128, BK=128, split-K=2 (KLEN=512), grid 512
    mfma_gemm<128, 128, 1024, 1024, EP_PARTIAL, 2><<<dim3(512), 256, 0, stream>>>(
        attn, woT, psWo0, nullptr, nullptr, (bf16*)psWo1, nullptr);

    // 6. Wo reduce + residual + LN2 (writes x2 and yln)
    wo_reduce_ln<<<ROWS, 256, 0, stream>>>(psWo0, psWo1, inp_bf,
                                           ln2_scale, ln2_bias, x2, yln);

    // 7. MLP1: 128x128 tile, BK=128, grid 1024
    mfma_gemm<128, 128, 4096, 1024, EP_GELU, 1><<<dim3(32 * 32), 256, 0, stream>>>(
        yln, w1T, hbuf, b1, nullptr, nullptr, nullptr);

    // 8. MLP2: 128x128, BK=128, split-K=2 (KLEN=2048), grid 512
    mfma_gemm<128, 128, 1024, 4096, EP_PARTIAL, 2><<<dim3(512), 256, 0, stream>>>(
        hbuf, w2T, out, nullptr, nullptr, (bf16*)psM2, nullptr);

    // 9. MLP2 reduce: out += psM2 + bias + x2
    mlp2_reduce<<<4096, 256, 0, stream>>>(out, psM2, b2, x2);
}

// Round 12
// 297.648 us; speedup vs baseline: 1.0046x; 1.0046x over previous
//
#include <hip/hip_runtime.h>
#include <math.h>
#include <stdint.h>

typedef __bf16 bf16;
typedef bf16  bf16x8 __attribute__((ext_vector_type(8)));
typedef float f32x4  __attribute__((ext_vector_type(4)));

// Problem constants
constexpr int Bb  = 2;
constexpr int Ss  = 2048;
constexpr int Dd  = 1024;
constexpr int Hh  = 16;
constexpr int DHh = 64;
constexpr int MLPd = 4096;
constexpr int ROWS = Bb * Ss;        // 4096
constexpr int NC  = Ss / 64;         // 32 chunks of 64
constexpr int BH  = Bb * Hh;         // 32
constexpr float EPS_LN = 1e-6f;
constexpr float KEPS   = 1e-3f;

// ---------------------------------------------------------------------------
// async global->LDS copy, 16B per lane (global_load_lds_dwordx4)
// ---------------------------------------------------------------------------
__device__ __forceinline__ void async_copy16(const bf16* g, bf16* l) {
    __builtin_amdgcn_global_load_lds(
        (__attribute__((address_space(1))) void*)g,
        (__attribute__((address_space(3))) void*)l,
        16, 0, 0);
}

// 64-wide swizzled LDS tile index (conflict-free fragment pattern)
__device__ __forceinline__ int swz64(int row, int col) {
    return row * 64 + (((col >> 3) ^ row) & 7) * 8 + (col & 7);
}

// ---------------------------------------------------------------------------
// Fused preprocessing: one dispatch, 16384 blocks x 256 threads.
//   sector 0: LN1 row + bf16 copy of inputs row
//   sector 1: 4x 1024x1024 weight convert+transpose
//   sector 2: w1 convert; sector 3: w2 convert
// ---------------------------------------------------------------------------
__global__ __launch_bounds__(256) void preproc_kernel(
    const float* __restrict__ inputs,
    const float* __restrict__ ln1_scale, const float* __restrict__ ln1_bias,
    bf16* __restrict__ xln, bf16* __restrict__ inp_bf,
    const float* __restrict__ wq, const float* __restrict__ wk,
    const float* __restrict__ wv, const float* __restrict__ wo,
    bf16* __restrict__ wqT, bf16* __restrict__ wkT,
    bf16* __restrict__ wvT, bf16* __restrict__ woT,
    const float* __restrict__ w1, bf16* __restrict__ w1T,
    const float* __restrict__ w2, bf16* __restrict__ w2T)
{
    __shared__ float tile[32][33];
    __shared__ float ssum[4], ssq[4];
    const int blk = blockIdx.x;
    const int sector = blk >> 12;

    if (sector == 0) {
        const int row = blk;
        const float* xr = inputs + (size_t)row * Dd;
        const int c0 = threadIdx.x * 4;
        float vals[4];
        float sum = 0.f, sumsq = 0.f;
#pragma unroll
        for (int i = 0; i < 4; i++) {
            float v = xr[c0 + i];
            vals[i] = v;
            sum += v;
            sumsq += v * v;
        }
#pragma unroll
        for (int off = 32; off > 0; off >>= 1) {
            sum   += __shfl_down(sum, off);
            sumsq += __shfl_down(sumsq, off);
        }
        const int wave = threadIdx.x >> 6;
        if ((threadIdx.x & 63) == 0) { ssum[wave] = sum; ssq[wave] = sumsq; }
        __syncthreads();
        const float tot   = ssum[0] + ssum[1] + ssum[2] + ssum[3];
        const float totsq = ssq[0] + ssq[1] + ssq[2] + ssq[3];
        const float mean = tot * (1.f / Dd);
        const float var  = totsq * (1.f / Dd) - mean * mean;
        const float r = rsqrtf(var + EPS_LN);
        bf16* orow = xln + (size_t)row * Dd;
        bf16* irow = inp_bf + (size_t)row * Dd;
#pragma unroll
        for (int i = 0; i < 4; i++) {
            irow[c0 + i] = (bf16)vals[i];
            orow[c0 + i] = (bf16)((vals[i] - mean) * r * ln1_scale[c0 + i] + ln1_bias[c0 + i]);
        }
    } else {
        const float* in; bf16* out; int K, N, bx, by;
        if (sector == 1) {
            const int local = blk - 4096;
            const int z = local >> 10;
            in  = (z == 0) ? wq : (z == 1) ? wk : (z == 2) ? wv : wo;
            out = (z == 0) ? wqT : (z == 1) ? wkT : (z == 2) ? wvT : woT;
            K = 1024; N = 1024;
            bx = local & 31; by = (local >> 5) & 31;
        } else if (sector == 2) {
            const int local = blk - 8192;
            in = w1; out = w1T; K = 1024; N = 4096;
            bx = local & 127; by = local >> 7;
        } else {
            const int local = blk - 12288;
            in = w2; out = w2T; K = 4096; N = 1024;
            bx = local & 31; by = local >> 5;
        }
        const int k0 = by * 32, n0 = bx * 32;
        const int tx = threadIdx.x & 31, ty = threadIdx.x >> 5;
#pragma unroll
        for (int i = 0; i < 32; i += 8)
            tile[ty + i][tx] = in[(size_t)(k0 + ty + i) * N + n0 + tx];
        __syncthreads();
#pragma unroll
        for (int i = 0; i < 32; i += 8)
            out[(size_t)(n0 + ty + i) * K + k0 + tx] = (bf16)tile[tx][ty + i];
    }
}

// ---------------------------------------------------------------------------
// LayerNorm (LN2): one block per row, 256 threads. bf16 in -> bf16 out.
// ---------------------------------------------------------------------------
__global__ __launch_bounds__(256) void ln_kernel(const bf16* __restrict__ x,
                                                 const float* __restrict__ scale,
                                                 const float* __restrict__ bias,
                                                 bf16* __restrict__ out)
{
    const int row = blockIdx.x;
    const bf16* xr = x + (size_t)row * Dd;
    const int c0 = threadIdx.x * 4;
    float vals[4];
    float sum = 0.f, sumsq = 0.f;
#pragma unroll
    for (int i = 0; i < 4; i++) {
        float v = (float)xr[c0 + i];
        vals[i] = v;
        sum += v;
        sumsq += v * v;
    }
#pragma unroll
    for (int off = 32; off > 0; off >>= 1) {
        sum   += __shfl_down(sum, off);
        sumsq += __shfl_down(sumsq, off);
    }
    __shared__ float ssum[4], ssq[4];
    const int wave = threadIdx.x >> 6;
    if ((threadIdx.x & 63) == 0) { ssum[wave] = sum; ssq[wave] = sumsq; }
    __syncthreads();
    const float tot   = ssum[0] + ssum[1] + ssum[2] + ssum[3];
    const float totsq = ssq[0] + ssq[1] + ssq[2] + ssq[3];
    const float mean = tot * (1.f / Dd);
    const float var  = totsq * (1.f / Dd) - mean * mean;
    const float r = rsqrtf(var + EPS_LN);
    bf16* orow = out + (size_t)row * Dd;
#pragma unroll
    for (int i = 0; i < 4; i++)
        orow[c0 + i] = (bf16)((vals[i] - mean) * r * scale[c0 + i] + bias[c0 + i]);
}

// ---------------------------------------------------------------------------
// MLP2 split-K reduce: out = psA(out) + psB + bias + x2.  grid 4096 x 256.
// ---------------------------------------------------------------------------
__global__ __launch_bounds__(256) void mlp2_reduce(
    float* __restrict__ outp, const float* __restrict__ psB,
    const float* __restrict__ b2, const bf16* __restrict__ x2)
{
    const size_t i4 = ((size_t)blockIdx.x * 256 + threadIdx.x) * 4;
    const int col = (int)(i4 & 1023);
    f32x4 a = *(const f32x4*)&outp[i4];
    f32x4 b = *(const f32x4*)&psB[i4];
    f32x4 o;
#pragma unroll
    for (int j = 0; j < 4; j++)
        o[j] = a[j] + b[j] + b2[col + j] + (float)x2[i4 + j];
    *(f32x4*)&outp[i4] = o;
}

// ---------------------------------------------------------------------------
// bf16 MFMA GEMM: C[4096, NDIM] = A @ B, BT[N][K], compile-time dims.
// 128 x TN tile; optional KSPLIT; 1-D grid, XCD-aware swizzle.
// Measured laws (R5-R11):
//  - binding resource = LDS staging volume M*N*K*2*(1/128+1/TN)
//  - effective staging BW rises with loads-in-flight: BK depth x blocks/CU
//    (BK=128 @2blk: 10.7-14 TB/s; BK=64 @2blk: 8.5 TB/s; 1blk: ~8 TB/s)
//  - per-shape optima: QKV 128/128@3blk; MLP1 256/64@2blk; Wo 64/128@2blk;
//    MLP2 splitK2 128/64@2blk
// ---------------------------------------------------------------------------
enum { EP_QKV = 0, EP_NONE = 1, EP_RES = 2, EP_GELU = 3, EP_BIAS_RES = 4, EP_PARTIAL = 5 };

template <int TN, int BK, int NDIM, int KDIM, int MODE, int KSPLIT>
__global__ __launch_bounds__(256, 2) void mfma_gemm(const bf16* __restrict__ A,
                                                    const bf16* __restrict__ BT,
                                                    void* __restrict__ Cout,
                                                    const float* __restrict__ bias,
                                                    const void* __restrict__ res,
                                                    bf16* __restrict__ out2,
                                                    bf16* __restrict__ out3)
{
    constexpr int WCT = TN / 2;      // wave col tile
    constexpr int NJ  = TN / 32;     // col fragments per wave
    constexpr int NS  = BK / 32;     // MFMA k-steps per tile
    constexpr int CPR = BK / 8;      // 16B chunks per row
    constexpr int RPI = 2048 / BK;   // rows staged per issue
    constexpr int GRIDY = 32;        // M/128
    constexpr int RPX = GRIDY / 8;   // row-blocks per XCD band (4)
    constexpr int TILES = GRIDY * (NDIM / TN);
    constexpr int KLEN  = KDIM / KSPLIT;
    __shared__ bf16 As[128 * BK];
    __shared__ bf16 Bs[TN * BK];
    const int t = threadIdx.x;
    const int wave = t >> 6, lane = t & 63;

    // K-split + XCD-aware block swizzle
    const int bid0 = blockIdx.x;
    const int ks  = (KSPLIT > 1) ? (bid0 / TILES) : 0;
    const int bid = (KSPLIT > 1) ? (bid0 % TILES) : bid0;
    const int xcd = bid & 7, idx = bid >> 3;
    const int row0 = (xcd * RPX + (idx & (RPX - 1))) * 128;
    const int col0 = (idx / RPX) * TN;

    const int wr = wave >> 1, wc = wave & 1;

    // staging indices
    const int srow = t / CPR;
    const int gch  = (t % CPR) ^ (srow & 7);
    const int sdst = t * 8;

    // hoisted global pointers (advance by BK per K-iter)
    const bf16* gA = A  + (size_t)(row0 + srow) * KDIM + ks * KLEN + gch * 8;
    const bf16* gB = BT + (size_t)(col0 + srow) * KDIM + ks * KLEN + gch * 8;

    // fragment indices
    const int m = lane & 15, quad = lane >> 4;
    const int mx7 = m & 7;

    f32x4 acc[4][NJ] = {};

    for (int k0 = 0; k0 < KLEN; k0 += BK) {
        __syncthreads();
#pragma unroll
        for (int i = 0; i < 128 / RPI; i++)
            async_copy16(gA + (size_t)i * RPI * KDIM, &As[i * 2048 + sdst]);
#pragma unroll
        for (int i = 0; i < TN / RPI; i++)
            async_copy16(gB + (size_t)i * RPI * KDIM, &Bs[i * 2048 + sdst]);
        __syncthreads();

#pragma unroll
        for (int s = 0; s < NS; s++) {
            const int pco = ((s * 4 + quad) ^ mx7) * 8;
            bf16x8 aF[4], bF[NJ];
#pragma unroll
            for (int i = 0; i < 4; i++)
                aF[i] = *(const bf16x8*)&As[(wr * 64 + i * 16 + m) * BK + pco];
#pragma unroll
            for (int j = 0; j < NJ; j++)
                bF[j] = *(const bf16x8*)&Bs[(wc * WCT + j * 16 + m) * BK + pco];
#pragma unroll
            for (int i = 0; i < 4; i++)
#pragma unroll
                for (int j = 0; j < NJ; j++)
                    acc[i][j] = __builtin_amdgcn_mfma_f32_16x16x32_bf16(
                        aF[i], bF[j], acc[i][j], 0, 0, 0);
        }
        gA += BK;
        gB += BK;
    }

    // epilogue: C/D layout col=lane&15, row=quad*4+reg (HW-verified)
#pragma unroll
    for (int i = 0; i < 4; i++) {
#pragma unroll
        for (int j = 0; j < NJ; j++) {
#pragma unroll
            for (int r = 0; r < 4; r++) {
                const int row = row0 + wr * 64 + i * 16 + quad * 4 + r;
                const int col = col0 + wc * WCT + j * 16 + m;
                float val = acc[i][j][r];
                if constexpr (MODE == EP_QKV) {
                    // per-element third routing
                    const int third = col >> 10;
                    bf16* dst = (third == 0) ? (bf16*)Cout : (third == 1) ? out2 : out3;
                    if (third < 2) val = fmaxf(val, 0.f) + KEPS;
                    dst[(size_t)row * 1024 + (col & 1023)] = (bf16)val;
                } else if constexpr (MODE == EP_NONE) {
                    ((bf16*)Cout)[(size_t)row * NDIM + col] = (bf16)val;
                } else if constexpr (MODE == EP_RES) {
                    val += (float)((const bf16*)res)[(size_t)row * NDIM + col];
                    ((bf16*)Cout)[(size_t)row * NDIM + col] = (bf16)val;
                } else if constexpr (MODE == EP_GELU) {
                    val += bias[col];
                    const float u = 0.7978845608028654f * (val + 0.044715f * val * val * val);
                    const float e = __expf(2.f * u);
                    val = val * (1.f - 1.f / (e + 1.f));
                    ((bf16*)Cout)[(size_t)row * NDIM + col] = (bf16)val;
                } else if constexpr (MODE == EP_BIAS_RES) {
                    val += bias[col] + (float)((const bf16*)res)[(size_t)row * NDIM + col];
                    ((float*)Cout)[(size_t)row * NDIM + col] = val;
                } else {
                    // EP_PARTIAL: raw fp32 partial; ks selects the buffer
                    float* dst = (ks == 0) ? (float*)Cout : (float*)out2;
                    dst[(size_t)row * NDIM + col] = val;
                }
            }
        }
    }
}

// ---------------------------------------------------------------------------
// Phase A (MFMA): KV[m][d], ksum[m]. kvs bf16. grid=(NC,BH)
// ---------------------------------------------------------------------------
__global__ __launch_bounds__(256) void chunk_kv_kernel(const bf16* __restrict__ phik,
                                                       const bf16* __restrict__ v,
                                                       bf16* __restrict__ kvs,
                                                       float* __restrict__ ksums)
{
    const int c = blockIdx.x, bh = blockIdx.y;
    const int b = bh >> 4, h = bh & 15;
    __shared__ bf16 Kt[64 * 64];   // [m][s]
    __shared__ bf16 Vt[64 * 64];   // [d][s]
    const int t = threadIdx.x;
    const int wave = t >> 6, lane = t & 63;
    const int m16 = lane & 15, quad = lane >> 4;
    const int wr = wave >> 1, wc = wave & 1;
    const int f = t & 63, s4 = t >> 6;

#pragma unroll
    for (int i = 0; i < 16; i++) {
        const int s = s4 + 4 * i;
        const size_t g = ((size_t)((b * Ss + c * 64 + s) * Hh + h)) * DHh + f;
        Kt[swz64(f, s)] = phik[g];
        Vt[swz64(f, s)] = v[g];
    }
    __syncthreads();

    f32x4 acc[2][2] = {};
#pragma unroll
    for (int ks = 0; ks < 2; ks++) {
        bf16x8 aF[2], bF[2];
#pragma unroll
        for (int i = 0; i < 2; i++)
            aF[i] = *(const bf16x8*)&Kt[swz64(wr * 32 + i * 16 + m16, ks * 32 + quad * 8)];
#pragma unroll
        for (int j = 0; j < 2; j++)
            bF[j] = *(const bf16x8*)&Vt[swz64(wc * 32 + j * 16 + m16, ks * 32 + quad * 8)];
#pragma unroll
        for (int i = 0; i < 2; i++)
#pragma unroll
            for (int j = 0; j < 2; j++)
                acc[i][j] = __builtin_amdgcn_mfma_f32_16x16x32_bf16(
                    aF[i], bF[j], acc[i][j], 0, 0, 0);
    }

    const size_t base = ((size_t)bh * NC + c) * 4096;
#pragma unroll
    for (int i = 0; i < 2; i++)
#pragma unroll
        for (int j = 0; j < 2; j++)
#pragma unroll
            for (int r = 0; r < 4; r++) {
                const int mrow = wr * 32 + i * 16 + quad * 4 + r;
                const int dcol = wc * 32 + j * 16 + m16;
                kvs[base + mrow * 64 + dcol] = (bf16)acc[i][j][r];
            }

    if (t < 64) {
        float s_ = 0.f;
#pragma unroll
        for (int p = 0; p < 8; p++) {
            bf16x8 k8 = *(const bf16x8*)&Kt[t * 64 + p * 8];
#pragma unroll
            for (int e = 0; e < 8; e++) s_ += (float)k8[e];
        }
        ksums[((size_t)bh * NC + c) * 64 + t] = s_;
    }
}

// ---------------------------------------------------------------------------
// Phase B: exclusive prefix scan over chunks, element-parallel. kvs bf16.
// ---------------------------------------------------------------------------
__global__ __launch_bounds__(256) void scan_kernel(bf16* __restrict__ kvs,
                                                   float* __restrict__ ksums)
{
    const int e  = blockIdx.x * 256 + threadIdx.x;
    const int bh = blockIdx.y;
    float run = 0.f;
#pragma unroll 4
    for (int c = 0; c < NC; c++) {
        const size_t idx = ((size_t)bh * NC + c) * 4096 + e;
        const float val = (float)kvs[idx];
        kvs[idx] = (bf16)run;
        run += val;
    }
    if (blockIdx.x == 0 && threadIdx.x < 64) {
        float r = 0.f;
        for (int c = 0; c < NC; c++) {
            const size_t idx = ((size_t)bh * NC + c) * 64 + threadIdx.x;
            const float val = ksums[idx];
            ksums[idx] = r;
            r += val;
        }
    }
}

// ---------------------------------------------------------------------------
// Phase C (MFMA): per-chunk output. grid = (NC, BH)
// ---------------------------------------------------------------------------
__global__ __launch_bounds__(256) void attn_out_kernel(const bf16* __restrict__ phiq,
                                                       const bf16* __restrict__ phik,
                                                       const bf16* __restrict__ v,
                                                       const bf16* __restrict__ kvs,
                                                       const float* __restrict__ ksums,
                                                       bf16* __restrict__ attn)
{
    const int c = blockIdx.x, bh = blockIdx.y;
    const int b = bh >> 4, h = bh & 15;
    __shared__ bf16 Qs [64 * 64];
    __shared__ bf16 KVb[64 * 64];
    __shared__ bf16 Sm [64 * 64];
    __shared__ bf16 KVt[64 * 64];
    __shared__ float ksm[64], den[64];
    const int t = threadIdx.x;
    const int wave = t >> 6, lane = t & 63;
    const int m16 = lane & 15, quad = lane >> 4;
    const int wr = wave >> 1, wc = wave & 1;
    const int f = t & 63, s4 = t >> 6;

#pragma unroll
    for (int i = 0; i < 16; i++) {
        const int s = s4 + 4 * i;
        const size_t g = ((size_t)((b * Ss + c * 64 + s) * Hh + h)) * DHh + f;
        Qs [swz64(s, f)] = phiq[g];
        KVb[swz64(s, f)] = phik[g];
    }
    if (t < 64) ksm[t] = ksums[((size_t)bh * NC + c) * 64 + t];
    __syncthreads();

    // S = phiq @ phik^T
    f32x4 sacc[2][2] = {};
#pragma unroll
    for (int ks = 0; ks < 2; ks++) {
        bf16x8 aF[2], bF[2];
#pragma unroll
        for (int i = 0; i < 2; i++)
            aF[i] = *(const bf16x8*)&Qs [swz64(wr * 32 + i * 16 + m16, ks * 32 + quad * 8)];
#pragma unroll
        for (int j = 0; j < 2; j++)
            bF[j] = *(const bf16x8*)&KVb[swz64(wc * 32 + j * 16 + m16, ks * 32 + quad * 8)];
#pragma unroll
        for (int i = 0; i < 2; i++)
#pragma unroll
            for (int j = 0; j < 2; j++)
                sacc[i][j] = __builtin_amdgcn_mfma_f32_16x16x32_bf16(
                    aF[i], bF[j], sacc[i][j], 0, 0, 0);
    }
#pragma unroll
    for (int i = 0; i < 2; i++)
#pragma unroll
        for (int j = 0; j < 2; j++)
#pragma unroll
            for (int r = 0; r < 4; r++) {
                const int row = wr * 32 + i * 16 + quad * 4 + r;
                const int col = wc * 32 + j * 16 + m16;
                Sm[swz64(row, col)] = (bf16)((col <= row) ? sacc[i][j][r] : 0.f);
            }
    __syncthreads();

    // stage Vt[d][s'] and KVt[d][m]
#pragma unroll
    for (int i = 0; i < 16; i++) {
        const int s = s4 + 4 * i;
        const size_t g = ((size_t)((b * Ss + c * 64 + s) * Hh + h)) * DHh + f;
        KVb[swz64(f, s)] = v[g];
    }
    {
        const size_t base = ((size_t)bh * NC + c) * 4096;
#pragma unroll
        for (int i = 0; i < 16; i++) {
            const int e = t + 256 * i;
            KVt[swz64(e & 63, e >> 6)] = kvs[base + e];
        }
    }
    __syncthreads();

    // den
    if (t < 64) {
        float d_ = 0.f;
#pragma unroll
        for (int p = 0; p < 8; p++) {
            const int gc = (p ^ (t & 7)) * 8;
            bf16x8 q8 = *(const bf16x8*)&Qs[t * 64 + p * 8];
            bf16x8 s8 = *(const bf16x8*)&Sm[t * 64 + p * 8];
#pragma unroll
            for (int e = 0; e < 8; e++)
                d_ += (float)q8[e] * ksm[gc + e] + (float)s8[e];
        }
        den[t] = d_;
    }

    // O = S @ v + phiq @ KV_excl
    f32x4 oacc[2][2] = {};
#pragma unroll
    for (int ks = 0; ks < 2; ks++) {
        bf16x8 aF[2], bF[2];
#pragma unroll
        for (int i = 0; i < 2; i++)
            aF[i] = *(const bf16x8*)&Sm [swz64(wr * 32 + i * 16 + m16, ks * 32 + quad * 8)];
#pragma unroll
        for (int j = 0; j < 2; j++)
            bF[j] = *(const bf16x8*)&KVb[swz64(wc * 32 + j * 16 + m16, ks * 32 + quad * 8)];
#pragma unroll
        for (int i = 0; i < 2; i++)
#pragma unroll
            for (int j = 0; j < 2; j++)
                oacc[i][j] = __builtin_amdgcn_mfma_f32_16x16x32_bf16(
                    aF[i], bF[j], oacc[i][j], 0, 0, 0);
    }
#pragma unroll
    for (int ks = 0; ks < 2; ks++) {
        bf16x8 aF[2], bF[2];
#pragma unroll
        for (int i = 0; i < 2; i++)
            aF[i] = *(const bf16x8*)&Qs [swz64(wr * 32 + i * 16 + m16, ks * 32 + quad * 8)];
#pragma unroll
        for (int j = 0; j < 2; j++)
            bF[j] = *(const bf16x8*)&KVt[swz64(wc * 32 + j * 16 + m16, ks * 32 + quad * 8)];
#pragma unroll
        for (int i = 0; i < 2; i++)
#pragma unroll
            for (int j = 0; j < 2; j++)
                oacc[i][j] = __builtin_amdgcn_mfma_f32_16x16x32_bf16(
                    aF[i], bF[j], oacc[i][j], 0, 0, 0);
    }
    __syncthreads();

#pragma unroll
    for (int i = 0; i < 2; i++) {
#pragma unroll
        for (int r = 0; r < 4; r++) {
            const int row = wr * 32 + i * 16 + quad * 4 + r;
            const float dinv = 1.f / den[row];
#pragma unroll
            for (int j = 0; j < 2; j++) {
                const int col = wc * 32 + j * 16 + m16;
                attn[((size_t)((b * Ss + c * 64 + row) * Hh + h)) * DHh + col] =
                    (bf16)(oacc[i][j][r] * dinv);
            }
        }
    }
}

// ---------------------------------------------------------------------------
// Host launch
// ---------------------------------------------------------------------------
extern "C" void kernel_launch(void* const* d_in, const int* in_sizes, int n_in,
                              void* d_out, int out_size, void* d_ws, size_t ws_size,
                              hipStream_t stream)
{
    const float* inputs    = (const float*)d_in[0];
    const float* ln1_scale = (const float*)d_in[1];
    const float* ln1_bias  = (const float*)d_in[2];
    const float* wq        = (const float*)d_in[3];
    const float* wk        = (const float*)d_in[4];
    const float* wv        = (const float*)d_in[5];
    const float* wo        = (const float*)d_in[6];
    const float* ln2_scale = (const float*)d_in[7];
    const float* ln2_bias  = (const float*)d_in[8];
    const float* w1        = (const float*)d_in[9];
    const float* b1        = (const float*)d_in[10];
    const float* w2        = (const float*)d_in[11];
    const float* b2        = (const float*)d_in[12];
    float* out = (float*)d_out;

    // Workspace layout (byte offsets), with lifetime reuse:
    //  0  MB: xln bf16 -> attn bf16 -> MLP2 partial1 (fp32, 0-16MB)
    //  8  MB: q bf16 -> yln bf16
    //  16 MB: k,v (16-32) -> hbuf (16-48)
    //  32 MB: kvs bf16 (32-40)
    //  48 MB: x2 bf16; 56 MB: inp_bf bf16
    //  64 MB: ksums; 64.25 MB: bf16 weights (24MB)
    char* ws = (char*)d_ws;
    bf16*  xln    = (bf16*)ws;
    bf16*  q      = (bf16*)(ws + (8ull  << 20));
    bf16*  k      = (bf16*)(ws + (16ull << 20));
    bf16*  v      = (bf16*)(ws + (24ull << 20));
    bf16*  kvs    = (bf16*)(ws + (32ull << 20));
    bf16*  x2     = (bf16*)(ws + (48ull << 20));
    bf16*  inp_bf = (bf16*)(ws + (56ull << 20));
    float* ksums  = (float*)(ws + (64ull << 20));
    bf16*  wqT    = (bf16*)(ws + (64ull << 20) + (1ull << 18));
    bf16*  wkT    = wqT + 1024 * 1024;
    bf16*  wvT    = wkT + 1024 * 1024;
    bf16*  woT    = wvT + 1024 * 1024;
    bf16*  w1T    = woT + 1024 * 1024;         // [4096][1024]
    bf16*  w2T    = w1T + 4096 * 1024;         // [1024][4096]
    bf16*  attn   = xln;
    bf16*  yln    = q;
    bf16*  hbuf   = k;                         // 32MB spanning 16-48MB
    float* psM2   = (float*)ws;                // 16MB (xln/attn dead by MLP2)

    // 0. Fused preprocessing
    preproc_kernel<<<16384, 256, 0, stream>>>(
        inputs, ln1_scale, ln1_bias, xln, inp_bf,
        wq, wk, wv, wo, wqT, wkT, wvT, woT, w1, w1T, w2, w2T);

    // 1. Fused QKV: 128x128, BK=128, grid 768 = 3 blocks/CU
    mfma_gemm<128, 128, 3072, 1024, EP_QKV, 1><<<dim3(24 * 32), 256, 0, stream>>>(
        xln, wqT, q, nullptr, nullptr, k, v);

    // 2-4. Chunked causal linear attention
    {
        dim3 gridA(NC, BH);
        chunk_kv_kernel<<<gridA, 256, 0, stream>>>(k, v, kvs, ksums);
        scan_kernel<<<dim3(4096 / 256, BH), 256, 0, stream>>>(kvs, ksums);
        attn_out_kernel<<<gridA, 256, 0, stream>>>(q, k, v, kvs, ksums, attn);
    }

    // 5. Wo: 64x128 tile, BK=128, direct EP_RES (no split), grid 512
    mfma_gemm<64, 128, 1024, 1024, EP_RES, 1><<<dim3(512), 256, 0, stream>>>(
        attn, woT, x2, nullptr, inp_bf, nullptr, nullptr);

    // 6. LN2
    ln_kernel<<<ROWS, 256, 0, stream>>>(x2, ln2_scale, ln2_bias, yln);

    // 7. MLP1: 128x256 tile, BK=64, grid 512 (R10 measured best: 47 us)
    mfma_gemm<256, 64, 4096, 1024, EP_GELU, 1><<<dim3(16 * 32), 256, 0, stream>>>(
        yln, w1T, hbuf, b1, nullptr, nullptr, nullptr);

    // 8. MLP2: 128x128, BK=64, split-K=2 (R10 config), grid 512
    mfma_gemm<128, 64, 1024, 4096, EP_PARTIAL, 2><<<dim3(512), 256, 0, stream>>>(
        hbuf, w2T, out, nullptr, nullptr, (bf16*)psM2, nullptr);

    // 9. MLP2 reduce: out += psM2 + bias + x2
    mlp2_reduce<<<4096, 256, 0, stream>>>(out, psM2, b2, x2);
}

// Round 13
// 283.435 us; speedup vs baseline: 1.0550x; 1.0501x over previous
//
#include <hip/hip_runtime.h>
#include <math.h>
#include <stdint.h>

typedef __bf16 bf16;
typedef bf16  bf16x8 __attribute__((ext_vector_type(8)));
typedef float f32x4  __attribute__((ext_vector_type(4)));

// Problem constants
constexpr int Bb  = 2;
constexpr int Ss  = 2048;
constexpr int Dd  = 1024;
constexpr int Hh  = 16;
constexpr int DHh = 64;
constexpr int MLPd = 4096;
constexpr int ROWS = Bb * Ss;        // 4096
constexpr int NC  = Ss / 64;         // 32 chunks of 64
constexpr int BH  = Bb * Hh;         // 32
constexpr float EPS_LN = 1e-6f;
constexpr float KEPS   = 1e-3f;

// ---------------------------------------------------------------------------
// async global->LDS copy, 16B per lane (global_load_lds_dwordx4)
// ---------------------------------------------------------------------------
__device__ __forceinline__ void async_copy16(const bf16* g, bf16* l) {
    __builtin_amdgcn_global_load_lds(
        (__attribute__((address_space(1))) void*)g,
        (__attribute__((address_space(3))) void*)l,
        16, 0, 0);
}

// 64-wide swizzled LDS tile index (conflict-free fragment pattern)
__device__ __forceinline__ int swz64(int row, int col) {
    return row * 64 + (((col >> 3) ^ row) & 7) * 8 + (col & 7);
}

// ---------------------------------------------------------------------------
// Fused preprocessing: one dispatch, 16384 blocks x 256 threads.
//   sector 0: LN1 row + bf16 copy of inputs row
//   sector 1: 4x 1024x1024 weight convert+transpose
//   sector 2: w1 convert; sector 3: w2 convert
// ---------------------------------------------------------------------------
__global__ __launch_bounds__(256) void preproc_kernel(
    const float* __restrict__ inputs,
    const float* __restrict__ ln1_scale, const float* __restrict__ ln1_bias,
    bf16* __restrict__ xln, bf16* __restrict__ inp_bf,
    const float* __restrict__ wq, const float* __restrict__ wk,
    const float* __restrict__ wv, const float* __restrict__ wo,
    bf16* __restrict__ wqT, bf16* __restrict__ wkT,
    bf16* __restrict__ wvT, bf16* __restrict__ woT,
    const float* __restrict__ w1, bf16* __restrict__ w1T,
    const float* __restrict__ w2, bf16* __restrict__ w2T)
{
    __shared__ float tile[32][33];
    __shared__ float ssum[4], ssq[4];
    const int blk = blockIdx.x;
    const int sector = blk >> 12;

    if (sector == 0) {
        const int row = blk;
        const float* xr = inputs + (size_t)row * Dd;
        const int c0 = threadIdx.x * 4;
        float vals[4];
        float sum = 0.f, sumsq = 0.f;
#pragma unroll
        for (int i = 0; i < 4; i++) {
            float v = xr[c0 + i];
            vals[i] = v;
            sum += v;
            sumsq += v * v;
        }
#pragma unroll
        for (int off = 32; off > 0; off >>= 1) {
            sum   += __shfl_down(sum, off);
            sumsq += __shfl_down(sumsq, off);
        }
        const int wave = threadIdx.x >> 6;
        if ((threadIdx.x & 63) == 0) { ssum[wave] = sum; ssq[wave] = sumsq; }
        __syncthreads();
        const float tot   = ssum[0] + ssum[1] + ssum[2] + ssum[3];
        const float totsq = ssq[0] + ssq[1] + ssq[2] + ssq[3];
        const float mean = tot * (1.f / Dd);
        const float var  = totsq * (1.f / Dd) - mean * mean;
        const float r = rsqrtf(var + EPS_LN);
        bf16* orow = xln + (size_t)row * Dd;
        bf16* irow = inp_bf + (size_t)row * Dd;
#pragma unroll
        for (int i = 0; i < 4; i++) {
            irow[c0 + i] = (bf16)vals[i];
            orow[c0 + i] = (bf16)((vals[i] - mean) * r * ln1_scale[c0 + i] + ln1_bias[c0 + i]);
        }
    } else {
        const float* in; bf16* out; int K, N, bx, by;
        if (sector == 1) {
            const int local = blk - 4096;
            const int z = local >> 10;
            in  = (z == 0) ? wq : (z == 1) ? wk : (z == 2) ? wv : wo;
            out = (z == 0) ? wqT : (z == 1) ? wkT : (z == 2) ? wvT : woT;
            K = 1024; N = 1024;
            bx = local & 31; by = (local >> 5) & 31;
        } else if (sector == 2) {
            const int local = blk - 8192;
            in = w1; out = w1T; K = 1024; N = 4096;
            bx = local & 127; by = local >> 7;
        } else {
            const int local = blk - 12288;
            in = w2; out = w2T; K = 4096; N = 1024;
            bx = local & 31; by = local >> 5;
        }
        const int k0 = by * 32, n0 = bx * 32;
        const int tx = threadIdx.x & 31, ty = threadIdx.x >> 5;
#pragma unroll
        for (int i = 0; i < 32; i += 8)
            tile[ty + i][tx] = in[(size_t)(k0 + ty + i) * N + n0 + tx];
        __syncthreads();
#pragma unroll
        for (int i = 0; i < 32; i += 8)
            out[(size_t)(n0 + ty + i) * K + k0 + tx] = (bf16)tile[tx][ty + i];
    }
}

// ---------------------------------------------------------------------------
// Wo split-K reduce + residual + LN2, one block per row (psA/psB bf16):
//   x2 = bf16(psA + psB + inp_bf);  yln = LN(x2)
// NOTE: yln may alias psA's memory — per-thread RAW order (read psA then
// write yln at identical index mapping) makes this safe.
// ---------------------------------------------------------------------------
__global__ __launch_bounds__(256) void wo_reduce_ln(
    const bf16* __restrict__ psA, const bf16* __restrict__ psB,
    const bf16* __restrict__ inp,
    const float* __restrict__ scale, const float* __restrict__ bias,
    bf16* __restrict__ x2, bf16* __restrict__ yln)
{
    const int row = blockIdx.x;
    const int c0 = threadIdx.x * 4;
    const size_t base = (size_t)row * Dd + c0;
    float vals[4];
    float sum = 0.f, sumsq = 0.f;
#pragma unroll
    for (int i = 0; i < 4; i++) {
        float v = (float)psA[base + i] + (float)psB[base + i] + (float)inp[base + i];
        v = (float)(bf16)v;      // x2 stored bf16; LN stats on rounded value
        vals[i] = v;
        sum += v;
        sumsq += v * v;
    }
#pragma unroll
    for (int off = 32; off > 0; off >>= 1) {
        sum   += __shfl_down(sum, off);
        sumsq += __shfl_down(sumsq, off);
    }
    __shared__ float ssum[4], ssq[4];
    const int wave = threadIdx.x >> 6;
    if ((threadIdx.x & 63) == 0) { ssum[wave] = sum; ssq[wave] = sumsq; }
    __syncthreads();
    const float tot   = ssum[0] + ssum[1] + ssum[2] + ssum[3];
    const float totsq = ssq[0] + ssq[1] + ssq[2] + ssq[3];
    const float mean = tot * (1.f / Dd);
    const float var  = totsq * (1.f / Dd) - mean * mean;
    const float r = rsqrtf(var + EPS_LN);
#pragma unroll
    for (int i = 0; i < 4; i++) {
        x2[base + i]  = (bf16)vals[i];
        yln[base + i] = (bf16)((vals[i] - mean) * r * scale[c0 + i] + bias[c0 + i]);
    }
}

// ---------------------------------------------------------------------------
// MLP2 split-K reduce: out = psA + psB + bias + x2 (psA/psB bf16).
// grid 4096 x 256, 4 elems/thread.
// ---------------------------------------------------------------------------
__global__ __launch_bounds__(256) void mlp2_reduce(
    float* __restrict__ outp,
    const bf16* __restrict__ psA, const bf16* __restrict__ psB,
    const float* __restrict__ b2, const bf16* __restrict__ x2)
{
    const size_t i4 = ((size_t)blockIdx.x * 256 + threadIdx.x) * 4;
    const int col = (int)(i4 & 1023);
    f32x4 o;
#pragma unroll
    for (int j = 0; j < 4; j++)
        o[j] = (float)psA[i4 + j] + (float)psB[i4 + j] + b2[col + j] + (float)x2[i4 + j];
    *(f32x4*)&outp[i4] = o;
}

// ---------------------------------------------------------------------------
// bf16 MFMA GEMM: C[4096, NDIM] = A @ B, BT[N][K], compile-time dims.
// 128 x TN tile; optional KSPLIT (bf16 partials); 1-D grid, XCD swizzle.
// Measured laws (R5-R12):
//  - binding resource = LDS staging volume M*N*K*2*(1/128+1/TN)
//  - effective staging BW ~8.5-14 TB/s depending on loads-in-flight
//    (BK depth x blocks/CU); >=2 blocks/CU mandatory
//  - per-shape optima (R10 = best total): QKV 192/64@2blk; Wo splitK2
//    128/64; MLP1 256/64@2blk; MLP2 splitK2 128/64
//  - config deltas beyond this are within +-3us run variance
// ---------------------------------------------------------------------------
enum { EP_QKV = 0, EP_NONE = 1, EP_RES = 2, EP_GELU = 3, EP_BIAS_RES = 4, EP_PARTIAL = 5 };

template <int TN, int BK, int NDIM, int KDIM, int MODE, int KSPLIT>
__global__ __launch_bounds__(256, 2) void mfma_gemm(const bf16* __restrict__ A,
                                                    const bf16* __restrict__ BT,
                                                    void* __restrict__ Cout,
                                                    const float* __restrict__ bias,
                                                    const void* __restrict__ res,
                                                    bf16* __restrict__ out2,
                                                    bf16* __restrict__ out3)
{
    constexpr int WCT = TN / 2;      // wave col tile
    constexpr int NJ  = TN / 32;     // col fragments per wave
    constexpr int NS  = BK / 32;     // MFMA k-steps per tile
    constexpr int CPR = BK / 8;      // 16B chunks per row
    constexpr int RPI = 2048 / BK;   // rows staged per issue
    constexpr int GRIDY = 32;        // M/128
    constexpr int RPX = GRIDY / 8;   // row-blocks per XCD band (4)
    constexpr int TILES = GRIDY * (NDIM / TN);
    constexpr int KLEN  = KDIM / KSPLIT;
    __shared__ bf16 As[128 * BK];
    __shared__ bf16 Bs[TN * BK];
    const int t = threadIdx.x;
    const int wave = t >> 6, lane = t & 63;

    // K-split + XCD-aware block swizzle
    const int bid0 = blockIdx.x;
    const int ks  = (KSPLIT > 1) ? (bid0 / TILES) : 0;
    const int bid = (KSPLIT > 1) ? (bid0 % TILES) : bid0;
    const int xcd = bid & 7, idx = bid >> 3;
    const int row0 = (xcd * RPX + (idx & (RPX - 1))) * 128;
    const int col0 = (idx / RPX) * TN;

    const int wr = wave >> 1, wc = wave & 1;

    // staging indices
    const int srow = t / CPR;
    const int gch  = (t % CPR) ^ (srow & 7);
    const int sdst = t * 8;

    // hoisted global pointers (advance by BK per K-iter)
    const bf16* gA = A  + (size_t)(row0 + srow) * KDIM + ks * KLEN + gch * 8;
    const bf16* gB = BT + (size_t)(col0 + srow) * KDIM + ks * KLEN + gch * 8;

    // fragment indices
    const int m = lane & 15, quad = lane >> 4;
    const int mx7 = m & 7;

    f32x4 acc[4][NJ] = {};

    for (int k0 = 0; k0 < KLEN; k0 += BK) {
        __syncthreads();
#pragma unroll
        for (int i = 0; i < 128 / RPI; i++)
            async_copy16(gA + (size_t)i * RPI * KDIM, &As[i * 2048 + sdst]);
#pragma unroll
        for (int i = 0; i < TN / RPI; i++)
            async_copy16(gB + (size_t)i * RPI * KDIM, &Bs[i * 2048 + sdst]);
        __syncthreads();

#pragma unroll
        for (int s = 0; s < NS; s++) {
            const int pco = ((s * 4 + quad) ^ mx7) * 8;
            bf16x8 aF[4], bF[NJ];
#pragma unroll
            for (int i = 0; i < 4; i++)
                aF[i] = *(const bf16x8*)&As[(wr * 64 + i * 16 + m) * BK + pco];
#pragma unroll
            for (int j = 0; j < NJ; j++)
                bF[j] = *(const bf16x8*)&Bs[(wc * WCT + j * 16 + m) * BK + pco];
#pragma unroll
            for (int i = 0; i < 4; i++)
#pragma unroll
                for (int j = 0; j < NJ; j++)
                    acc[i][j] = __builtin_amdgcn_mfma_f32_16x16x32_bf16(
                        aF[i], bF[j], acc[i][j], 0, 0, 0);
        }
        gA += BK;
        gB += BK;
    }

    // epilogue: C/D layout col=lane&15, row=quad*4+reg (HW-verified)
#pragma unroll
    for (int i = 0; i < 4; i++) {
#pragma unroll
        for (int j = 0; j < NJ; j++) {
#pragma unroll
            for (int r = 0; r < 4; r++) {
                const int row = row0 + wr * 64 + i * 16 + quad * 4 + r;
                const int col = col0 + wc * WCT + j * 16 + m;
                float val = acc[i][j][r];
                if constexpr (MODE == EP_QKV) {
                    // per-element third routing (TN=192 tiles straddle 1024)
                    const int third = col >> 10;
                    bf16* dst = (third == 0) ? (bf16*)Cout : (third == 1) ? out2 : out3;
                    if (third < 2) val = fmaxf(val, 0.f) + KEPS;
                    dst[(size_t)row * 1024 + (col & 1023)] = (bf16)val;
                } else if constexpr (MODE == EP_NONE) {
                    ((bf16*)Cout)[(size_t)row * NDIM + col] = (bf16)val;
                } else if constexpr (MODE == EP_RES) {
                    val += (float)((const bf16*)res)[(size_t)row * NDIM + col];
                    ((bf16*)Cout)[(size_t)row * NDIM + col] = (bf16)val;
                } else if constexpr (MODE == EP_GELU) {
                    val += bias[col];
                    // gelu(x) ~ x * sigmoid(1.702 x)  (one exp; error <= ~0.02)
                    val = val / (1.f + __expf(-1.702f * val));
                    ((bf16*)Cout)[(size_t)row * NDIM + col] = (bf16)val;
                } else if constexpr (MODE == EP_BIAS_RES) {
                    val += bias[col] + (float)((const bf16*)res)[(size_t)row * NDIM + col];
                    ((float*)Cout)[(size_t)row * NDIM + col] = val;
                } else {
                    // EP_PARTIAL: bf16 partial; ks selects the buffer
                    bf16* dst = (ks == 0) ? (bf16*)Cout : out2;
                    dst[(size_t)row * NDIM + col] = (bf16)val;
                }
            }
        }
    }
}

// ---------------------------------------------------------------------------
// Phase A (MFMA): KV[m][d], ksum[m]. kvs bf16. grid=(NC,BH)
// ---------------------------------------------------------------------------
__global__ __launch_bounds__(256) void chunk_kv_kernel(const bf16* __restrict__ phik,
                                                       const bf16* __restrict__ v,
                                                       bf16* __restrict__ kvs,
                                                       float* __restrict__ ksums)
{
    const int c = blockIdx.x, bh = blockIdx.y;
    const int b = bh >> 4, h = bh & 15;
    __shared__ bf16 Kt[64 * 64];   // [m][s]
    __shared__ bf16 Vt[64 * 64];   // [d][s]
    const int t = threadIdx.x;
    const int wave = t >> 6, lane = t & 63;
    const int m16 = lane & 15, quad = lane >> 4;
    const int wr = wave >> 1, wc = wave & 1;
    const int f = t & 63, s4 = t >> 6;

#pragma unroll
    for (int i = 0; i < 16; i++) {
        const int s = s4 + 4 * i;
        const size_t g = ((size_t)((b * Ss + c * 64 + s) * Hh + h)) * DHh + f;
        Kt[swz64(f, s)] = phik[g];
        Vt[swz64(f, s)] = v[g];
    }
    __syncthreads();

    f32x4 acc[2][2] = {};
#pragma unroll
    for (int ks = 0; ks < 2; ks++) {
        bf16x8 aF[2], bF[2];
#pragma unroll
        for (int i = 0; i < 2; i++)
            aF[i] = *(const bf16x8*)&Kt[swz64(wr * 32 + i * 16 + m16, ks * 32 + quad * 8)];
#pragma unroll
        for (int j = 0; j < 2; j++)
            bF[j] = *(const bf16x8*)&Vt[swz64(wc * 32 + j * 16 + m16, ks * 32 + quad * 8)];
#pragma unroll
        for (int i = 0; i < 2; i++)
#pragma unroll
            for (int j = 0; j < 2; j++)
                acc[i][j] = __builtin_amdgcn_mfma_f32_16x16x32_bf16(
                    aF[i], bF[j], acc[i][j], 0, 0, 0);
    }

    const size_t base = ((size_t)bh * NC + c) * 4096;
#pragma unroll
    for (int i = 0; i < 2; i++)
#pragma unroll
        for (int j = 0; j < 2; j++)
#pragma unroll
            for (int r = 0; r < 4; r++) {
                const int mrow = wr * 32 + i * 16 + quad * 4 + r;
                const int dcol = wc * 32 + j * 16 + m16;
                kvs[base + mrow * 64 + dcol] = (bf16)acc[i][j][r];
            }

    if (t < 64) {
        float s_ = 0.f;
#pragma unroll
        for (int p = 0; p < 8; p++) {
            bf16x8 k8 = *(const bf16x8*)&Kt[t * 64 + p * 8];
#pragma unroll
            for (int e = 0; e < 8; e++) s_ += (float)k8[e];
        }
        ksums[((size_t)bh * NC + c) * 64 + t] = s_;
    }
}

// ---------------------------------------------------------------------------
// Phase B: exclusive prefix scan over chunks, element-parallel. kvs bf16.
// ---------------------------------------------------------------------------
__global__ __launch_bounds__(256) void scan_kernel(bf16* __restrict__ kvs,
                                                   float* __restrict__ ksums)
{
    const int e  = blockIdx.x * 256 + threadIdx.x;
    const int bh = blockIdx.y;
    float run = 0.f;
#pragma unroll 4
    for (int c = 0; c < NC; c++) {
        const size_t idx = ((size_t)bh * NC + c) * 4096 + e;
        const float val = (float)kvs[idx];
        kvs[idx] = (bf16)run;
        run += val;
    }
    if (blockIdx.x == 0 && threadIdx.x < 64) {
        float r = 0.f;
        for (int c = 0; c < NC; c++) {
            const size_t idx = ((size_t)bh * NC + c) * 64 + threadIdx.x;
            const float val = ksums[idx];
            ksums[idx] = r;
            r += val;
        }
    }
}

// ---------------------------------------------------------------------------
// Phase C (MFMA): per-chunk output. grid = (NC, BH)
// ---------------------------------------------------------------------------
__global__ __launch_bounds__(256) void attn_out_kernel(const bf16* __restrict__ phiq,
                                                       const bf16* __restrict__ phik,
                                                       const bf16* __restrict__ v,
                                                       const bf16* __restrict__ kvs,
                                                       const float* __restrict__ ksums,
                                                       bf16* __restrict__ attn)
{
    const int c = blockIdx.x, bh = blockIdx.y;
    const int b = bh >> 4, h = bh & 15;
    __shared__ bf16 Qs [64 * 64];
    __shared__ bf16 KVb[64 * 64];
    __shared__ bf16 Sm [64 * 64];
    __shared__ bf16 KVt[64 * 64];
    __shared__ float ksm[64], den[64];
    const int t = threadIdx.x;
    const int wave = t >> 6, lane = t & 63;
    const int m16 = lane & 15, quad = lane >> 4;
    const int wr = wave >> 1, wc = wave & 1;
    const int f = t & 63, s4 = t >> 6;

#pragma unroll
    for (int i = 0; i < 16; i++) {
        const int s = s4 + 4 * i;
        const size_t g = ((size_t)((b * Ss + c * 64 + s) * Hh + h)) * DHh + f;
        Qs [swz64(s, f)] = phiq[g];
        KVb[swz64(s, f)] = phik[g];
    }
    if (t < 64) ksm[t] = ksums[((size_t)bh * NC + c) * 64 + t];
    __syncthreads();

    // S = phiq @ phik^T
    f32x4 sacc[2][2] = {};
#pragma unroll
    for (int ks = 0; ks < 2; ks++) {
        bf16x8 aF[2], bF[2];
#pragma unroll
        for (int i = 0; i < 2; i++)
            aF[i] = *(const bf16x8*)&Qs [swz64(wr * 32 + i * 16 + m16, ks * 32 + quad * 8)];
#pragma unroll
        for (int j = 0; j < 2; j++)
            bF[j] = *(const bf16x8*)&KVb[swz64(wc * 32 + j * 16 + m16, ks * 32 + quad * 8)];
#pragma unroll
        for (int i = 0; i < 2; i++)
#pragma unroll
            for (int j = 0; j < 2; j++)
                sacc[i][j] = __builtin_amdgcn_mfma_f32_16x16x32_bf16(
                    aF[i], bF[j], sacc[i][j], 0, 0, 0);
    }
#pragma unroll
    for (int i = 0; i < 2; i++)
#pragma unroll
        for (int j = 0; j < 2; j++)
#pragma unroll
            for (int r = 0; r < 4; r++) {
                const int row = wr * 32 + i * 16 + quad * 4 + r;
                const int col = wc * 32 + j * 16 + m16;
                Sm[swz64(row, col)] = (bf16)((col <= row) ? sacc[i][j][r] : 0.f);
            }
    __syncthreads();

    // stage Vt[d][s'] and KVt[d][m]
#pragma unroll
    for (int i = 0; i < 16; i++) {
        const int s = s4 + 4 * i;
        const size_t g = ((size_t)((b * Ss + c * 64 + s) * Hh + h)) * DHh + f;
        KVb[swz64(f, s)] = v[g];
    }
    {
        const size_t base = ((size_t)bh * NC + c) * 4096;
#pragma unroll
        for (int i = 0; i < 16; i++) {
            const int e = t + 256 * i;
            KVt[swz64(e & 63, e >> 6)] = kvs[base + e];
        }
    }
    __syncthreads();

    // den
    if (t < 64) {
        float d_ = 0.f;
#pragma unroll
        for (int p = 0; p < 8; p++) {
            const int gc = (p ^ (t & 7)) * 8;
            bf16x8 q8 = *(const bf16x8*)&Qs[t * 64 + p * 8];
            bf16x8 s8 = *(const bf16x8*)&Sm[t * 64 + p * 8];
#pragma unroll
            for (int e = 0; e < 8; e++)
                d_ += (float)q8[e] * ksm[gc + e] + (float)s8[e];
        }
        den[t] = d_;
    }

    // O = S @ v + phiq @ KV_excl
    f32x4 oacc[2][2] = {};
#pragma unroll
    for (int ks = 0; ks < 2; ks++) {
        bf16x8 aF[2], bF[2];
#pragma unroll
        for (int i = 0; i < 2; i++)
            aF[i] = *(const bf16x8*)&Sm [swz64(wr * 32 + i * 16 + m16, ks * 32 + quad * 8)];
#pragma unroll
        for (int j = 0; j < 2; j++)
            bF[j] = *(const bf16x8*)&KVb[swz64(wc * 32 + j * 16 + m16, ks * 32 + quad * 8)];
#pragma unroll
        for (int i = 0; i < 2; i++)
#pragma unroll
            for (int j = 0; j < 2; j++)
                oacc[i][j] = __builtin_amdgcn_mfma_f32_16x16x32_bf16(
                    aF[i], bF[j], oacc[i][j], 0, 0, 0);
    }
#pragma unroll
    for (int ks = 0; ks < 2; ks++) {
        bf16x8 aF[2], bF[2];
#pragma unroll
        for (int i = 0; i < 2; i++)
            aF[i] = *(const bf16x8*)&Qs [swz64(wr * 32 + i * 16 + m16, ks * 32 + quad * 8)];
#pragma unroll
        for (int j = 0; j < 2; j++)
            bF[j] = *(const bf16x8*)&KVt[swz64(wc * 32 + j * 16 + m16, ks * 32 + quad * 8)];
#pragma unroll
        for (int i = 0; i < 2; i++)
#pragma unroll
            for (int j = 0; j < 2; j++)
                oacc[i][j] = __builtin_amdgcn_mfma_f32_16x16x32_bf16(
                    aF[i], bF[j], oacc[i][j], 0, 0, 0);
    }
    __syncthreads();

#pragma unroll
    for (int i = 0; i < 2; i++) {
#pragma unroll
        for (int r = 0; r < 4; r++) {
            const int row = wr * 32 + i * 16 + quad * 4 + r;
            const float dinv = 1.f / den[row];
#pragma unroll
            for (int j = 0; j < 2; j++) {
                const int col = wc * 32 + j * 16 + m16;
                attn[((size_t)((b * Ss + c * 64 + row) * Hh + h)) * DHh + col] =
                    (bf16)(oacc[i][j][r] * dinv);
            }
        }
    }
}

// ---------------------------------------------------------------------------
// Host launch
// ---------------------------------------------------------------------------
extern "C" void kernel_launch(void* const* d_in, const int* in_sizes, int n_in,
                              void* d_out, int out_size, void* d_ws, size_t ws_size,
                              hipStream_t stream)
{
    const float* inputs    = (const float*)d_in[0];
    const float* ln1_scale = (const float*)d_in[1];
    const float* ln1_bias  = (const float*)d_in[2];
    const float* wq        = (const float*)d_in[3];
    const float* wk        = (const float*)d_in[4];
    const float* wv        = (const float*)d_in[5];
    const float* wo        = (const float*)d_in[6];
    const float* ln2_scale = (const float*)d_in[7];
    const float* ln2_bias  = (const float*)d_in[8];
    const float* w1        = (const float*)d_in[9];
    const float* b1        = (const float*)d_in[10];
    const float* w2        = (const float*)d_in[11];
    const float* b2        = (const float*)d_in[12];
    float* out = (float*)d_out;

    // Workspace layout (byte offsets), with lifetime reuse:
    //  0  MB: xln bf16 -> attn bf16 -> MLP2 partial A (bf16, 0-8)
    //  8  MB: q bf16 -> Wo partial A (bf16) -> yln bf16 -> MLP2 partial B
    //  16 MB: k bf16 -> Wo partial B (bf16) -> hbuf (16-48)
    //  24 MB: v bf16
    //  32 MB: kvs bf16 (32-40)
    //  48 MB: x2 bf16; 56 MB: inp_bf bf16
    //  64 MB: ksums; 64.25 MB: bf16 weights (24MB)
    char* ws = (char*)d_ws;
    bf16*  xln    = (bf16*)ws;
    bf16*  q      = (bf16*)(ws + (8ull  << 20));
    bf16*  k      = (bf16*)(ws + (16ull << 20));
    bf16*  v      = (bf16*)(ws + (24ull << 20));
    bf16*  kvs    = (bf16*)(ws + (32ull << 20));
    bf16*  x2     = (bf16*)(ws + (48ull << 20));
    bf16*  inp_bf = (bf16*)(ws + (56ull << 20));
    float* ksums  = (float*)(ws + (64ull << 20));
    bf16*  wqT    = (bf16*)(ws + (64ull << 20) + (1ull << 18));
    bf16*  wkT    = wqT + 1024 * 1024;
    bf16*  wvT    = wkT + 1024 * 1024;
    bf16*  woT    = wvT + 1024 * 1024;
    bf16*  w1T    = woT + 1024 * 1024;         // [4096][1024]
    bf16*  w2T    = w1T + 4096 * 1024;         // [1024][4096]
    bf16*  attn   = xln;
    bf16*  yln    = q;                         // aliases psWoA (safe: see kernel)
    bf16*  hbuf   = k;                         // 32MB spanning 16-48MB
    bf16*  psWoA  = q;                         // q dead after attn_out
    bf16*  psWoB  = k;                         // k dead after attn_out
    bf16*  psM2A  = xln;                       // attn dead after Wo
    bf16*  psM2B  = (bf16*)(ws + (8ull << 20) + (4ull << 20)); // after yln? no:
    // yln (8-16) is read by MLP1 and dead after; place psM2B at 24MB (v dead).
    psM2B = v;

    // 0. Fused preprocessing
    preproc_kernel<<<16384, 256, 0, stream>>>(
        inputs, ln1_scale, ln1_bias, xln, inp_bf,
        wq, wk, wv, wo, wqT, wkT, wvT, woT, w1, w1T, w2, w2T);

    // 1. Fused QKV: 128x192 tile, BK=64, grid 512 = 2 blocks/CU (R10 best)
    mfma_gemm<192, 64, 3072, 1024, EP_QKV, 1><<<dim3(512), 256, 0, stream>>>(
        xln, wqT, q, nullptr, nullptr, k, v);

    // 2-4. Chunked causal linear attention
    {
        dim3 gridA(NC, BH);
        chunk_kv_kernel<<<gridA, 256, 0, stream>>>(k, v, kvs, ksums);
        scan_kernel<<<dim3(4096 / 256, BH), 256, 0, stream>>>(kvs, ksums);
        attn_out_kernel<<<gridA, 256, 0, stream>>>(q, k, v, kvs, ksums, attn);
    }

    // 5. Wo: 128x128, BK=64, split-K=2, grid 512; bf16 partials
    mfma_gemm<128, 64, 1024, 1024, EP_PARTIAL, 2><<<dim3(512), 256, 0, stream>>>(
        attn, woT, psWoA, nullptr, nullptr, psWoB, nullptr);

    // 6. Wo reduce + residual + LN2 (writes x2 and yln; yln aliases psWoA)
    wo_reduce_ln<<<ROWS, 256, 0, stream>>>(psWoA, psWoB, inp_bf,
                                           ln2_scale, ln2_bias, x2, yln);

    // 7. MLP1: 128x256 tile, BK=64, grid 512 (R10 best); sigmoid-gelu
    mfma_gemm<256, 64, 4096, 1024, EP_GELU, 1><<<dim3(16 * 32), 256, 0, stream>>>(
        yln, w1T, hbuf, b1, nullptr, nullptr, nullptr);

    // 8. MLP2: 128x128, BK=64, split-K=2, grid 512; bf16 partials
    mfma_gemm<128, 64, 1024, 4096, EP_PARTIAL, 2><<<dim3(512), 256, 0, stream>>>(
        hbuf, w2T, psM2A, nullptr, nullptr, psM2B, nullptr);

    // 9. MLP2 reduce: out = psM2A + psM2B + bias + x2
    mlp2_reduce<<<4096, 256, 0, stream>>>(out, psM2A, psM2B, b2, x2);
}